// Round 6
// baseline (249.525 us; speedup 1.0000x reference)
//
#include <hip/hip_runtime.h>
#include <math.h>

#define HW 9216
#define CIN 128
#define COUT 256
#define RS 136   // A-tile row stride in shorts

typedef __attribute__((ext_vector_type(8))) short short8;
typedef __attribute__((ext_vector_type(4))) float f32x4;

static __device__ __forceinline__ unsigned short f2bf(float f) {
  union { float f; unsigned u; } v; v.f = f;
  unsigned r = v.u + 0x7FFF + ((v.u >> 16) & 1);
  return (unsigned short)(r >> 16);
}
static __device__ __forceinline__ float bflo(unsigned u) {
  union { unsigned u; float f; } v; v.u = u << 16; return v.f;
}
static __device__ __forceinline__ float bfhi(unsigned u) {
  union { unsigned u; float f; } v; v.u = u & 0xffff0000u; return v.f;
}

// ---------------- single prep kernel ----------------
// blocks 0..1151:    x NCHW fp32 -> xTb NHWC bf16
// blocks 1152..2303: wS = main weights, MFMA B-frag order [tap][w][ks][nt][lane][8]
// blocks 2304..2447: wAf = offset/mask weights, frag order [tap][ks][nt2][lane][8]
// blocks 2448..4751: out[b][n][hw] = bias[n]  (split-K blocks atomicAdd on top)
__global__ __launch_bounds__(256) void k_prep(const float* __restrict__ x,
                                              unsigned short* __restrict__ xTb,
                                              unsigned short* __restrict__ wS,
                                              unsigned short* __restrict__ wAf,
                                              const float* __restrict__ wgt,
                                              const float* __restrict__ offw,
                                              const float* __restrict__ modw,
                                              const float* __restrict__ bias,
                                              float* __restrict__ out) {
  __shared__ float tile[32][129];
  int bid = blockIdx.x;
  int t = threadIdx.x;
  if (bid < 1152) {
    int wseg = bid % 3, h = (bid / 3) % 96, b = bid / 288;
    int wl = t & 31, cg = t >> 5;
    const float* xp = x + ((size_t)(b * 128 + cg) * 96 + h) * 96 + wseg * 32 + wl;
#pragma unroll
    for (int i = 0; i < 16; ++i)
      tile[wl][cg + 8 * i] = xp[(size_t)8 * i * HW];
    __syncthreads();
    int cl = t & 127, wg = t >> 7;
    unsigned short* op = xTb + (((size_t)(b * 96 + h) * 96) + wseg * 32) * 128 + cl;
#pragma unroll
    for (int i = 0; i < 16; ++i)
      op[(size_t)(wg + 2 * i) * 128] = f2bf(tile[wg + 2 * i][cl]);
  } else if (bid < 2304) {
    int i = (bid - 1152) * 256 + t;           // < 294912
    int j = i & 7, l = (i >> 3) & 63, frag = i >> 9;
    int nt = frag & 3, ks = (frag >> 2) & 3, w = (frag >> 4) & 3, tap = frag >> 6;
    int n = w * 64 + nt * 16 + (l & 15);
    int c = ks * 32 + (l >> 4) * 8 + j;
    wS[i] = f2bf(wgt[n * 1152 + c * 9 + tap]);
  } else if (bid < 2448) {
    int i = (bid - 2304) * 256 + t;           // < 36864
    int j = i & 7, l = (i >> 3) & 63, frag = i >> 9;   // frag < 72
    int nt = frag & 1, ks = (frag >> 1) & 3, tap = frag >> 3;
    int n = nt * 16 + (l & 15);
    int c = ks * 32 + (l >> 4) * 8 + j;
    float v = 0.f;
    if (n < 18) v = offw[n * 1152 + c * 9 + tap];
    else if (n < 27) v = modw[(n - 18) * 1152 + c * 9 + tap];
    wAf[i] = f2bf(v);
  } else {
    int base = (bid - 2448) * 4096;
#pragma unroll
    for (int j = 0; j < 16; ++j) {
      int idx = base + j * 256 + t;
      int n = (idx / HW) & 255;
      out[idx] = bias[n];
    }
  }
}

// ---------------- offset/mask conv (standalone MFMA) ----------------
// 576 blocks (XCD-swizzled) x 256 thr. 64 px, N=32, K=18x64 integer taps.
// Writes om[B][27][HW] fp32 (offsets bias-added, mask sigmoided).
__global__ __launch_bounds__(256) void k_off(const unsigned short* __restrict__ xTb,
                                             const unsigned short* __restrict__ wAf,
                                             const float* __restrict__ offb,
                                             const float* __restrict__ modb,
                                             float* __restrict__ om) {
  __shared__ __align__(16) unsigned short Ab[2][64 * RS];   // 34816 B
  int t = threadIdx.x;
  int l = t & 63, w = t >> 6;
  int lm = l & 15, lq = l >> 4;
  int raw = blockIdx.x;
  int bid = (raw & 7) * 72 + (raw >> 3);
  int pix0 = bid * 64;
  int b = pix0 / HW;
  int posim0 = pix0 % HW;
  int ibase = b * HW;

  int px1 = t >> 2, cq = t & 3;            // 4 threads per px, 32 c each
  int pos1 = posim0 + px1;
  int ho1 = pos1 / 96, wo1 = pos1 % 96;
  f32x4 acc2[2];
  acc2[0] = (f32x4){0.f, 0.f, 0.f, 0.f};
  acc2[1] = (f32x4){0.f, 0.f, 0.f, 0.f};
  uint4 p[4];
  bool pv;

#define LOAD1(KP)                                                             \
  {                                                                           \
    int kp_ = (KP);                                                           \
    int hy = ho1 + kp_ / 3 - 1, hx = wo1 + kp_ % 3 - 1;                       \
    pv = ((unsigned)hy < 96u) && ((unsigned)hx < 96u);                        \
    int hyc = min(max(hy, 0), 95), hxc = min(max(hx, 0), 95);                 \
    const unsigned short* s = xTb + (size_t)(ibase + hyc * 96 + hxc) * 128 + cq * 32; \
    p[0] = *(const uint4*)(s);      p[1] = *(const uint4*)(s + 8);            \
    p[2] = *(const uint4*)(s + 16); p[3] = *(const uint4*)(s + 24);           \
  }
#define STORE1(BUF)                                                           \
  {                                                                           \
    unsigned short* dst = Ab[BUF] + px1 * RS + cq * 32;                       \
    uint4 z = {0u, 0u, 0u, 0u};                                               \
    *(uint4*)(dst)      = pv ? p[0] : z;  *(uint4*)(dst + 8)  = pv ? p[1] : z; \
    *(uint4*)(dst + 16) = pv ? p[2] : z;  *(uint4*)(dst + 24) = pv ? p[3] : z; \
  }

  LOAD1(0);
  STORE1(0);
  __syncthreads();
  for (int h = 0; h < 9; ++h) {
    if (h < 8) LOAD1(h + 1);
    const unsigned short* Asrc = Ab[h & 1];
#pragma unroll
    for (int ks = 0; ks < 4; ++ks) {
      short8 af = *(short8*)(Asrc + (w * 16 + lm) * RS + ks * 32 + lq * 8);
#pragma unroll
      for (int nt = 0; nt < 2; ++nt) {
        short8 bfr = *(const short8*)(wAf + (size_t)(((h * 4 + ks) * 2 + nt) * 64 + l) * 8);
        acc2[nt] = __builtin_amdgcn_mfma_f32_16x16x32_bf16(af, bfr, acc2[nt], 0, 0, 0);
      }
    }
    if (h < 8) STORE1((h + 1) & 1);
    __syncthreads();
  }
#undef LOAD1
#undef STORE1

  // epilogue: block transpose (reuse Ab), bias + sigmoid, coalesced store
  float* oz = (float*)Ab;   // [32][68]
#pragma unroll
  for (int nt = 0; nt < 2; ++nt) {
    int n = nt * 16 + lm;
#pragma unroll
    for (int r = 0; r < 4; ++r) {
      float v = acc2[nt][r];
      if (n < 18) v += offb[n];
      else if (n < 27) { v += modb[n - 18]; v = 1.f / (1.f + expf(-v)); }
      oz[n * 68 + w * 16 + lq * 4 + r] = v;
    }
  }
  __syncthreads();
#pragma unroll
  for (int pass = 0; pass < 7; ++pass) {
    int n = pass * 4 + (t >> 6);
    if (n < 27)
      om[((size_t)b * 27 + n) * HW + posim0 + l] = oz[n * 68 + l];
  }
}

// ---------------- main deformable GEMM: split-K x3 ----------------
// 1728 blocks x 256 thr. Block = 64 px x 256 n x 3 taps; atomicAdd epilogue.
// XCD swizzle keeps one M-tile's 3 splits on one XCD.
__global__ __launch_bounds__(256) void k_main(const unsigned short* __restrict__ xTb,
                                              const unsigned short* __restrict__ wS,
                                              const float* __restrict__ om,
                                              float* __restrict__ out) {
  __shared__ __align__(16) unsigned short Ab[2][64 * RS];   // 34816 B

  int t = threadIdx.x;
  int l = t & 63, w = t >> 6;
  int lm = l & 15, lq = l >> 4;
  int raw = blockIdx.x;
  int xcd = raw & 7;
  int r2 = raw >> 3;               // 0..215
  int split = r2 % 3;
  int bid = xcd * 72 + r2 / 3;     // 0..575
  int pix0 = bid * 64;
  int b = pix0 / HW;
  int posim0 = pix0 % HW;
  int ibase = b * HW;

  int px = t & 63;
  int pos = posim0 + px;
  int ho = pos / 96, wo = pos % 96;
  const float* omp = om + (size_t)b * 27 * HW + pos;
  int kp0 = split * 3;

  f32x4 acc[4][4];
#pragma unroll
  for (int i = 0; i < 4; ++i)
#pragma unroll
    for (int j = 0; j < 4; ++j)
      acc[i][j] = (f32x4){0.f, 0.f, 0.f, 0.f};

  float w00, w01, w10, w11;
  int o00, o01, o10, o11;
  int cb0 = w * 16, cb1 = 64 + w * 16;

#define GEO(KP)                                                              \
  {                                                                          \
    int kp_ = (KP);                                                          \
    float dy = omp[(size_t)(2 * kp_) * HW];                                  \
    float dx = omp[(size_t)(2 * kp_ + 1) * HW];                              \
    float mk = omp[(size_t)(18 + kp_) * HW];                                 \
    float py = (float)(ho - 1 + kp_ / 3) + dy;                               \
    float pxf = (float)(wo - 1 + kp_ % 3) + dx;                              \
    float fy = floorf(py), fx = floorf(pxf);                                 \
    int y0 = (int)fy, x0 = (int)fx;                                          \
    float ly = py - fy, lx = pxf - fx;                                       \
    w00 = (1.f - ly) * (1.f - lx); w01 = (1.f - ly) * lx;                    \
    w10 = ly * (1.f - lx);         w11 = ly * lx;                            \
    bool vy0 = (unsigned)y0 < 96u, vy1 = (unsigned)(y0 + 1) < 96u;           \
    bool vx0 = (unsigned)x0 < 96u, vx1 = (unsigned)(x0 + 1) < 96u;           \
    w00 = (vy0 && vx0) ? w00 * mk : 0.f;                                     \
    w01 = (vy0 && vx1) ? w01 * mk : 0.f;                                     \
    w10 = (vy1 && vx0) ? w10 * mk : 0.f;                                     \
    w11 = (vy1 && vx1) ? w11 * mk : 0.f;                                     \
    int y0c = min(max(y0, 0), 95), y1c = min(max(y0 + 1, 0), 95);            \
    int x0c = min(max(x0, 0), 95), x1c = min(max(x0 + 1, 0), 95);            \
    o00 = (ibase + y0c * 96 + x0c) * 128;                                    \
    o01 = (ibase + y0c * 96 + x1c) * 128;                                    \
    o10 = (ibase + y1c * 96 + x0c) * 128;                                    \
    o11 = (ibase + y1c * 96 + x1c) * 128;                                    \
  }

  uint4 g[8];
#define GATHER(CB)                                                           \
  {                                                                          \
    g[0] = *(const uint4*)(xTb + o00 + (CB));                                \
    g[1] = *(const uint4*)(xTb + o00 + (CB) + 8);                            \
    g[2] = *(const uint4*)(xTb + o01 + (CB));                                \
    g[3] = *(const uint4*)(xTb + o01 + (CB) + 8);                            \
    g[4] = *(const uint4*)(xTb + o10 + (CB));                                \
    g[5] = *(const uint4*)(xTb + o10 + (CB) + 8);                            \
    g[6] = *(const uint4*)(xTb + o11 + (CB));                                \
    g[7] = *(const uint4*)(xTb + o11 + (CB) + 8);                            \
  }
#define INTERP_WRITE(CB, BUF)                                                \
  {                                                                          \
    unsigned short* dst = Ab[BUF] + px * RS + (CB);                          \
    _Pragma("unroll")                                                        \
    for (int i = 0; i < 2; ++i) {                                            \
      unsigned qa[4] = {g[i].x, g[i].y, g[i].z, g[i].w};                     \
      unsigned qb[4] = {g[2 + i].x, g[2 + i].y, g[2 + i].z, g[2 + i].w};     \
      unsigned qc[4] = {g[4 + i].x, g[4 + i].y, g[4 + i].z, g[4 + i].w};     \
      unsigned qd[4] = {g[6 + i].x, g[6 + i].y, g[6 + i].z, g[6 + i].w};     \
      union { short8 v; unsigned short s[8]; } r;                            \
      _Pragma("unroll")                                                      \
      for (int j = 0; j < 4; ++j) {                                          \
        float lo = w00 * bflo(qa[j]) + w01 * bflo(qb[j]) + w10 * bflo(qc[j]) + w11 * bflo(qd[j]); \
        float hi = w00 * bfhi(qa[j]) + w01 * bfhi(qb[j]) + w10 * bfhi(qc[j]) + w11 * bfhi(qd[j]); \
        r.s[2 * j] = f2bf(lo);                                               \
        r.s[2 * j + 1] = f2bf(hi);                                           \
      }                                                                      \
      *(short8*)(dst + i * 8) = r.v;                                         \
    }                                                                        \
  }
#define MF(KP, KS)                                                           \
  {                                                                          \
    short8 af[4];                                                            \
    _Pragma("unroll")                                                        \
    for (int mt = 0; mt < 4; ++mt)                                           \
      af[mt] = *(short8*)(Asrc + (mt * 16 + lm) * RS + (KS) * 32 + lq * 8);  \
    _Pragma("unroll")                                                        \
    for (int nt = 0; nt < 4; ++nt) {                                         \
      short8 bfr = *(const short8*)(wS + (size_t)(((((KP) * 4 + w) * 4 + (KS)) * 4 + nt) * 64 + l) * 8); \
      _Pragma("unroll")                                                      \
      for (int mt = 0; mt < 4; ++mt)                                         \
        acc[mt][nt] = __builtin_amdgcn_mfma_f32_16x16x32_bf16(af[mt], bfr, acc[mt][nt], 0, 0, 0); \
    }                                                                        \
  }

  GEO(kp0);
  GATHER(cb0);
  INTERP_WRITE(cb0, 0);
  GATHER(cb1);
  INTERP_WRITE(cb1, 0);
  __syncthreads();

  for (int hh = 0; hh < 3; ++hh) {
    int kp = kp0 + hh;
    const unsigned short* Asrc = Ab[hh & 1];
    if (hh < 2) { GEO(kp + 1); GATHER(cb0); }
    MF(kp, 0); MF(kp, 1);
    if (hh < 2) { INTERP_WRITE(cb0, (hh + 1) & 1); GATHER(cb1); }
    MF(kp, 2); MF(kp, 3);
    if (hh < 2) { INTERP_WRITE(cb1, (hh + 1) & 1); }
    __syncthreads();
  }
#undef GEO
#undef GATHER
#undef INTERP_WRITE
#undef MF

  // ---- epilogue: per-wave LDS transpose -> coalesced atomicAdd ----
  float* ez = (float*)Ab + w * 1088;   // 64*17 floats per wave
#pragma unroll
  for (int nt = 0; nt < 4; ++nt) {
#pragma unroll
    for (int mt = 0; mt < 4; ++mt)
#pragma unroll
      for (int r = 0; r < 4; ++r)
        ez[(mt * 16 + lq * 4 + r) * 17 + lm] = acc[mt][nt][r];
    float* ob = out + ((size_t)(b * COUT + w * 64 + nt * 16)) * HW + posim0;
#pragma unroll
    for (int j = 0; j < 16; ++j)
      atomicAdd(&ob[(size_t)j * HW + l], ez[l * 17 + j]);
  }
}

extern "C" void kernel_launch(void* const* d_in, const int* in_sizes, int n_in,
                              void* d_out, int out_size, void* d_ws, size_t ws_size,
                              hipStream_t stream) {
  const float* x      = (const float*)d_in[0];
  const float* weight = (const float*)d_in[1];
  const float* bias   = (const float*)d_in[2];
  const float* offw   = (const float*)d_in[3];
  const float* offb   = (const float*)d_in[4];
  const float* modw   = (const float*)d_in[5];
  const float* modb   = (const float*)d_in[6];
  float* out = (float*)d_out;

  unsigned short* xTb = (unsigned short*)d_ws;          // 4718592 us
  unsigned short* wS  = xTb + 4718592;                  // 294912 us
  unsigned short* wAf = wS + 294912;                    // 36864 us
  float* om = (float*)(wAf + 36864);                    // 995328 f
  // total ws use ~14.1 MB

  k_prep<<<4752, 256, 0, stream>>>(x, xTb, wS, wAf, weight, offw, modw, bias, out);
  k_off<<<576, 256, 0, stream>>>(xTb, wAf, offb, modb, om);
  k_main<<<1728, 256, 0, stream>>>(xTb, wS, om, out);
}

// Round 7
// 213.813 us; speedup vs baseline: 1.1670x; 1.1670x over previous
//
#include <hip/hip_runtime.h>
#include <math.h>

#define HW 9216
#define CIN 128
#define COUT 256
#define RS 136   // A-tile row stride in shorts

typedef __attribute__((ext_vector_type(8))) short short8;
typedef __attribute__((ext_vector_type(4))) float f32x4;

static __device__ __forceinline__ unsigned short f2bf(float f) {
  union { float f; unsigned u; } v; v.f = f;
  unsigned r = v.u + 0x7FFF + ((v.u >> 16) & 1);
  return (unsigned short)(r >> 16);
}
static __device__ __forceinline__ float bflo(unsigned u) {
  union { unsigned u; float f; } v; v.u = u << 16; return v.f;
}
static __device__ __forceinline__ float bfhi(unsigned u) {
  union { unsigned u; float f; } v; v.u = u & 0xffff0000u; return v.f;
}

// async global->LDS, 16B per lane; LDS dst wave-uniform, lane i lands at dst+i*16
#define GLL16(gsrc, ldst)                                                     \
  __builtin_amdgcn_global_load_lds(                                           \
      (const __attribute__((address_space(1))) void*)(gsrc),                  \
      (__attribute__((address_space(3))) void*)(ldst), 16, 0, 0)

#define WAIT_VM4() __builtin_amdgcn_s_waitcnt(0x0F74)   // vmcnt(4), no lgkm/exp wait
#define WAIT_VM0() __builtin_amdgcn_s_waitcnt(0x0F70)   // vmcnt(0)

// ---------------- single prep kernel (same as R6) ----------------
__global__ __launch_bounds__(256) void k_prep(const float* __restrict__ x,
                                              unsigned short* __restrict__ xTb,
                                              unsigned short* __restrict__ wS,
                                              unsigned short* __restrict__ wAf,
                                              const float* __restrict__ wgt,
                                              const float* __restrict__ offw,
                                              const float* __restrict__ modw,
                                              const float* __restrict__ bias,
                                              float* __restrict__ out) {
  __shared__ float tile[32][129];
  int bid = blockIdx.x;
  int t = threadIdx.x;
  if (bid < 1152) {
    int wseg = bid % 3, h = (bid / 3) % 96, b = bid / 288;
    int wl = t & 31, cg = t >> 5;
    const float* xp = x + ((size_t)(b * 128 + cg) * 96 + h) * 96 + wseg * 32 + wl;
#pragma unroll
    for (int i = 0; i < 16; ++i)
      tile[wl][cg + 8 * i] = xp[(size_t)8 * i * HW];
    __syncthreads();
    int cl = t & 127, wg = t >> 7;
    unsigned short* op = xTb + (((size_t)(b * 96 + h) * 96) + wseg * 32) * 128 + cl;
#pragma unroll
    for (int i = 0; i < 16; ++i)
      op[(size_t)(wg + 2 * i) * 128] = f2bf(tile[wg + 2 * i][cl]);
  } else if (bid < 2304) {
    int i = (bid - 1152) * 256 + t;
    int j = i & 7, l = (i >> 3) & 63, frag = i >> 9;
    int nt = frag & 3, ks = (frag >> 2) & 3, w = (frag >> 4) & 3, tap = frag >> 6;
    int n = w * 64 + nt * 16 + (l & 15);
    int c = ks * 32 + (l >> 4) * 8 + j;
    wS[i] = f2bf(wgt[n * 1152 + c * 9 + tap]);
  } else if (bid < 2448) {
    int i = (bid - 2304) * 256 + t;
    int j = i & 7, l = (i >> 3) & 63, frag = i >> 9;
    int nt = frag & 1, ks = (frag >> 1) & 3, tap = frag >> 3;
    int n = nt * 16 + (l & 15);
    int c = ks * 32 + (l >> 4) * 8 + j;
    float v = 0.f;
    if (n < 18) v = offw[n * 1152 + c * 9 + tap];
    else if (n < 27) v = modw[(n - 18) * 1152 + c * 9 + tap];
    wAf[i] = f2bf(v);
  } else {
    int base = (bid - 2448) * 4096;
#pragma unroll
    for (int j = 0; j < 16; ++j) {
      int idx = base + j * 256 + t;
      int n = (idx / HW) & 255;
      out[idx] = bias[n];
    }
  }
}

// ---------------- offset/mask conv: GLL-staged contiguous taps ----------------
// 576 blocks x 256 thr. 64 px, N=32, 9 integer taps; A staged async (contiguous).
__global__ __launch_bounds__(256) void k_off(const unsigned short* __restrict__ xTb,
                                             const unsigned short* __restrict__ wAf,
                                             const float* __restrict__ offb,
                                             const float* __restrict__ modb,
                                             float* __restrict__ om) {
  __shared__ __align__(16) unsigned short Ab2[2][64 * 128];   // 32768 B
  int t = threadIdx.x;
  int l = t & 63, w = t >> 6;
  int lm = l & 15, lq = l >> 4;
  int raw = blockIdx.x;
  int bid = (raw & 7) * 72 + (raw >> 3);
  int pix0 = bid * 64;
  int b = pix0 / HW;
  int posim0 = pix0 % HW;
  int ibase = b * HW;

  f32x4 acc2[2];
  acc2[0] = (f32x4){0.f, 0.f, 0.f, 0.f};
  acc2[1] = (f32x4){0.f, 0.f, 0.f, 0.f};

  // wave stages px [w*16, w*16+16): 4 GLL, each = 4 px rows (lane: pxsub=l>>4, cpart=l&15)
  auto issue_off = [&](int h, int buf) {
#pragma unroll
    for (int j = 0; j < 4; ++j) {
      int p = w * 16 + j * 4 + (l >> 4);
      int sp = posim0 + p + (h / 3 - 1) * 96 + (h % 3 - 1);
      sp = min(max(sp, 0), HW - 1);
      const unsigned short* src = xTb + ((size_t)(ibase + sp)) * 128 + (l & 15) * 8;
      GLL16(src, &Ab2[buf][(w * 16 + j * 4) * 128]);
    }
  };
  int pfx = t >> 2, pcq = t & 3;
  int ppos = posim0 + pfx;
  int pho = ppos / 96, pwo = ppos % 96;

  issue_off(0, 0);
  for (int h = 0; h < 9; ++h) {
    WAIT_VM0();
    // zero invalid rows (x/y edges)
    {
      int hy = pho + h / 3 - 1, hx = pwo + h % 3 - 1;
      if ((unsigned)hy >= 96u || (unsigned)hx >= 96u) {
        uint4 z = {0u, 0u, 0u, 0u};
        unsigned short* d = &Ab2[h & 1][pfx * 128 + pcq * 32];
        *(uint4*)(d) = z; *(uint4*)(d + 8) = z;
        *(uint4*)(d + 16) = z; *(uint4*)(d + 24) = z;
      }
    }
    __syncthreads();
    if (h < 8) { __builtin_amdgcn_sched_barrier(0); issue_off(h + 1, (h + 1) & 1); }
    const unsigned short* Asrc = Ab2[h & 1];
#pragma unroll
    for (int ks = 0; ks < 4; ++ks) {
      short8 af = *(short8*)(Asrc + (w * 16 + lm) * 128 + ks * 32 + lq * 8);
#pragma unroll
      for (int nt = 0; nt < 2; ++nt) {
        short8 bfr = *(const short8*)(wAf + (size_t)(((h * 4 + ks) * 2 + nt) * 64 + l) * 8);
        acc2[nt] = __builtin_amdgcn_mfma_f32_16x16x32_bf16(af, bfr, acc2[nt], 0, 0, 0);
      }
    }
    __syncthreads();
  }

  // epilogue: block transpose (reuse Ab2), bias + sigmoid, coalesced store
  float* oz = (float*)Ab2;   // [32][68]
#pragma unroll
  for (int nt = 0; nt < 2; ++nt) {
    int n = nt * 16 + lm;
#pragma unroll
    for (int r = 0; r < 4; ++r) {
      float v = acc2[nt][r];
      if (n < 18) v += offb[n];
      else if (n < 27) { v += modb[n - 18]; v = 1.f / (1.f + expf(-v)); }
      oz[n * 68 + w * 16 + lq * 4 + r] = v;
    }
  }
  __syncthreads();
#pragma unroll
  for (int pass = 0; pass < 7; ++pass) {
    int n = pass * 4 + (t >> 6);
    if (n < 27)
      om[((size_t)b * 27 + n) * HW + posim0 + l] = oz[n * 68 + l];
  }
}

// ---------------- main deformable GEMM: async corner staging + split-K x3 ----
// 1728 blocks x 256 thr. Per wave-tap: 4 quanta of 4 px; 1 GLL stages one px's
// 4 corner rows (1KB) into wave-private LDS zone; interp LDS->Atile; MFMA.
__global__ __launch_bounds__(256, 3) void k_main(const unsigned short* __restrict__ xTb,
                                                 const unsigned short* __restrict__ wS,
                                                 const float* __restrict__ om,
                                                 float* __restrict__ out) {
  __shared__ __align__(16) unsigned short cornerZ[4][2][4][520];  // 33280 B
  __shared__ __align__(16) unsigned short Atile[64 * RS];         // 17408 B
  __shared__ float geoZ[4][16][8];                                // 2048 B

  int t = threadIdx.x;
  int l = t & 63, w = t >> 6;
  int lm = l & 15, lq = l >> 4;
  int raw = blockIdx.x;
  int xcd = raw & 7;
  int r2 = raw >> 3;
  int split = r2 % 3;
  int bid = xcd * 72 + r2 / 3;
  int pix0 = bid * 64;
  int b = pix0 / HW;
  int posim0 = pix0 % HW;
  int ibase = b * HW;
  int kp0 = split * 3;

  // geometry lane responsibility: px-in-wave = l&15
  int pxk = l & 15;
  int gpos = posim0 + w * 16 + pxk;
  int gho = gpos / 96, gwo = gpos % 96;
  const float* omg = om + (size_t)b * 27 * HW + gpos;

  f32x4 acc[4][4];
#pragma unroll
  for (int i = 0; i < 4; ++i)
#pragma unroll
    for (int j = 0; j < 4; ++j)
      acc[i][j] = (f32x4){0.f, 0.f, 0.f, 0.f};

  auto geow = [&](int kp) {
    float dy = omg[(size_t)(2 * kp) * HW];
    float dx = omg[(size_t)(2 * kp + 1) * HW];
    float mk = omg[(size_t)(18 + kp) * HW];
    float py = (float)(gho - 1 + kp / 3) + dy;
    float pxf = (float)(gwo - 1 + kp % 3) + dx;
    float fy = floorf(py), fx = floorf(pxf);
    int y0 = (int)fy, x0 = (int)fx;
    float ly = py - fy, lx = pxf - fx;
    float w00 = (1.f - ly) * (1.f - lx), w01 = (1.f - ly) * lx;
    float w10 = ly * (1.f - lx),         w11 = ly * lx;
    bool vy0 = (unsigned)y0 < 96u, vy1 = (unsigned)(y0 + 1) < 96u;
    bool vx0 = (unsigned)x0 < 96u, vx1 = (unsigned)(x0 + 1) < 96u;
    w00 = (vy0 && vx0) ? w00 * mk : 0.f;
    w01 = (vy0 && vx1) ? w01 * mk : 0.f;
    w10 = (vy1 && vx0) ? w10 * mk : 0.f;
    w11 = (vy1 && vx1) ? w11 * mk : 0.f;
    int y0c = min(max(y0, 0), 95), y1c = min(max(y0 + 1, 0), 95);
    int x0c = min(max(x0, 0), 95), x1c = min(max(x0 + 1, 0), 95);
    if (lq == 0) {
      float* gz = &geoZ[w][pxk][0];
      gz[0] = w00; gz[1] = w01; gz[2] = w10; gz[3] = w11;
      gz[4] = __int_as_float((ibase + y0c * 96 + x0c) * 128);
      gz[5] = __int_as_float((ibase + y0c * 96 + x1c) * 128);
      gz[6] = __int_as_float((ibase + y1c * 96 + x0c) * 128);
      gz[7] = __int_as_float((ibase + y1c * 96 + x1c) * 128);
    }
  };

  // stage quantum s: 4 px, one GLL each (lane: corner=l>>4, cpart=l&15)
  auto issue = [&](int s) {
    int q = s & 3, slot = s & 1;
#pragma unroll
    for (int i = 0; i < 4; ++i) {
      int o = __float_as_int(geoZ[w][q * 4 + i][4 + (l >> 4)]);
      const unsigned short* src = xTb + o + (l & 15) * 8;
      GLL16(src, &cornerZ[w][slot][i][0]);
    }
  };

  // interp quantum s from LDS corners -> Atile rows
  auto interp = [&](int s) {
    int q = s & 3, slot = s & 1;
    int pxq = q * 4 + (l >> 4);
    f32x4 wv = *(f32x4*)&geoZ[w][pxq][0];
    const unsigned short* cb = &cornerZ[w][slot][l >> 4][0];
    int co = (l & 15) * 8;
    uint4 qa = *(const uint4*)(cb + co);
    uint4 qb = *(const uint4*)(cb + 128 + co);
    uint4 qc = *(const uint4*)(cb + 256 + co);
    uint4 qd = *(const uint4*)(cb + 384 + co);
    unsigned aa[4] = {qa.x, qa.y, qa.z, qa.w};
    unsigned bb[4] = {qb.x, qb.y, qb.z, qb.w};
    unsigned cc[4] = {qc.x, qc.y, qc.z, qc.w};
    unsigned dd[4] = {qd.x, qd.y, qd.z, qd.w};
    union { short8 v; unsigned short sarr[8]; } r;
#pragma unroll
    for (int j = 0; j < 4; ++j) {
      float lo = wv[0] * bflo(aa[j]) + wv[1] * bflo(bb[j]) + wv[2] * bflo(cc[j]) + wv[3] * bflo(dd[j]);
      float hi = wv[0] * bfhi(aa[j]) + wv[1] * bfhi(bb[j]) + wv[2] * bfhi(cc[j]) + wv[3] * bfhi(dd[j]);
      r.sarr[2 * j] = f2bf(lo);
      r.sarr[2 * j + 1] = f2bf(hi);
    }
    *(short8*)(Atile + (w * 16 + pxq) * RS + co) = r.v;
  };

  auto mfma_tap = [&](int kp) {
#pragma unroll
    for (int ks = 0; ks < 4; ++ks) {
      short8 af[4];
#pragma unroll
      for (int mt = 0; mt < 4; ++mt)
        af[mt] = *(short8*)(Atile + (mt * 16 + lm) * RS + ks * 32 + lq * 8);
#pragma unroll
      for (int nt = 0; nt < 4; ++nt) {
        short8 bfr = *(const short8*)(wS + (size_t)((((kp * 4 + w) * 4 + ks) * 4 + nt) * 64 + l) * 8);
#pragma unroll
        for (int mt = 0; mt < 4; ++mt)
          acc[mt][nt] = __builtin_amdgcn_mfma_f32_16x16x32_bf16(af[mt], bfr, acc[mt][nt], 0, 0, 0);
      }
    }
  };

  geow(kp0);
  issue(0);
  issue(1);
  for (int h = 0; h < 3; ++h) {
#pragma unroll
    for (int q = 0; q < 4; ++q) {
      int s = 4 * h + q;
      if (q == 3) WAIT_VM0(); else WAIT_VM4();
      interp(s);
      if (q < 2) { __builtin_amdgcn_sched_barrier(0); issue(s + 2); }
    }
    __syncthreads();                 // Atile(h) complete; nothing in flight
    if (h < 2) {
      geow(kp0 + h + 1);
      __builtin_amdgcn_sched_barrier(0);
      issue(4 * h + 4);
      issue(4 * h + 5);              // latency rides over MFMA + barrier drain
    }
    mfma_tap(kp0 + h);
    __syncthreads();                 // Atile consumed; drains next-tap GLLs
  }

  // ---- epilogue: per-wave LDS transpose -> coalesced atomicAdd ----
  float* ez = (float*)Atile + w * 1088;   // 64*17 floats per wave
#pragma unroll
  for (int nt = 0; nt < 4; ++nt) {
#pragma unroll
    for (int mt = 0; mt < 4; ++mt)
#pragma unroll
      for (int r = 0; r < 4; ++r)
        ez[(mt * 16 + lq * 4 + r) * 17 + lm] = acc[mt][nt][r];
    float* ob = out + ((size_t)(b * COUT + w * 64 + nt * 16)) * HW + posim0;
#pragma unroll
    for (int j = 0; j < 16; ++j)
      atomicAdd(&ob[(size_t)j * HW + l], ez[l * 17 + j]);
  }
}

extern "C" void kernel_launch(void* const* d_in, const int* in_sizes, int n_in,
                              void* d_out, int out_size, void* d_ws, size_t ws_size,
                              hipStream_t stream) {
  const float* x      = (const float*)d_in[0];
  const float* weight = (const float*)d_in[1];
  const float* bias   = (const float*)d_in[2];
  const float* offw   = (const float*)d_in[3];
  const float* offb   = (const float*)d_in[4];
  const float* modw   = (const float*)d_in[5];
  const float* modb   = (const float*)d_in[6];
  float* out = (float*)d_out;

  unsigned short* xTb = (unsigned short*)d_ws;          // 4718592 us
  unsigned short* wS  = xTb + 4718592;                  // 294912 us
  unsigned short* wAf = wS + 294912;                    // 36864 us
  float* om = (float*)(wAf + 36864);                    // 995328 f
  // total ws use ~14.1 MB

  k_prep<<<4752, 256, 0, stream>>>(x, xTb, wS, wAf, weight, offw, modw, bias, out);
  k_off<<<576, 256, 0, stream>>>(xTb, wAf, offb, modb, om);
  k_main<<<1728, 256, 0, stream>>>(xTb, wS, om, out);
}